// Round 4
// baseline (1060.922 us; speedup 1.0000x reference)
//
#include <hip/hip_runtime.h>
#include <hip/hip_fp16.h>
#include <math.h>

#define B_   16
#define T_   24
#define HH_  96
#define WW_  96
#define HW_  (HH_ * WW_)
#define NMT_ 576   // 16-point m-tiles per frame (9216/16)

typedef __attribute__((ext_vector_type(8))) short short8v;  // 8 bf16
typedef __attribute__((ext_vector_type(4))) float f32x4;

__device__ __forceinline__ unsigned short f2bf(float x) {
    union { float f; unsigned u; } v; v.f = x;
    unsigned u = v.u + 0x7FFFu + ((v.u >> 16) & 1u);
    return (unsigned short)(u >> 16);
}
__device__ __forceinline__ float bf2f(unsigned short b) {
    union { unsigned u; float f; } v; v.u = ((unsigned)b) << 16; return v.f;
}
__device__ __forceinline__ float sigm(float x) { return 1.0f / (1.0f + expf(-x)); }

// ---------------------------------------------------------------------------
// Pack W and U into B-fragment order, bf16 hi/lo, tap-paired K.
// K-tile kt (k=0..31): k = lsec*8+e ; tap = 2*kt + (lsec>>1), ch = (lsec&1)*8+e.
// n = nt*16 + lm  (original Keras channel order: gate = nt, filter = lm).
// Buffer index: ((kt*4+nt)*64+lane)*8+e.  tap==9 -> zero pad.
// ---------------------------------------------------------------------------
__global__ void pack_w(const float* __restrict__ Wk, const float* __restrict__ Uk,
                       unsigned short* __restrict__ Wph, unsigned short* __restrict__ Wpl,
                       unsigned short* __restrict__ Uph, unsigned short* __restrict__ Upl) {
    int idx = blockIdx.x * 256 + threadIdx.x;
    if (idx >= 5 * 4 * 64 * 8) return;
    int e    = idx & 7;
    int lane = (idx >> 3) & 63;
    int nt   = (idx >> 9) & 3;
    int kt   = idx >> 11;
    int lsec = lane >> 4, lm = lane & 15;
    int tap  = 2 * kt + (lsec >> 1);
    int ch   = (lsec & 1) * 8 + e;
    int n    = nt * 16 + lm;
    float wv = 0.f, uv = 0.f;
    if (tap < 9) {
        wv = Wk[(tap * 16 + ch) * 64 + n];
        uv = Uk[(tap * 16 + ch) * 64 + n];
    }
    unsigned short wh = f2bf(wv), uh = f2bf(uv);
    Wph[idx] = wh; Wpl[idx] = f2bf(wv - bf2f(wh));
    Uph[idx] = uh; Upl[idx] = f2bf(uv - bf2f(uh));
}

// ---------------------------------------------------------------------------
// Phase 1: xz[b,t] = conv(x_t, W) + bias, all frames in parallel.
// Block: 256 thr = 4 waves, 4 image rows (wave w -> row y0+w), N=64/wave.
// LDS: (4+2) x 98 cells of 80 B ([hi0][hi1][lo0][lo1][pad]) + 1 zero cell.
// Output: f16 in C-fragment layout: uint2 index ((frame*576+mt)*4+nt)*64+lane.
// ---------------------------------------------------------------------------
__global__ __launch_bounds__(256) void xconv(
    const float* __restrict__ inputs,
    const unsigned short* __restrict__ Wph, const unsigned short* __restrict__ Wpl,
    const float* __restrict__ bias,
    __half* __restrict__ xz)
{
    __shared__ __align__(16) char lds[589 * 80];
    const int tid = threadIdx.x;
    const int y0  = blockIdx.x * 4;
    const int t   = blockIdx.y, b = blockIdx.z;
    const float* xf = inputs + ((size_t)(b * T_ + t)) * (HW_ * 16);

    for (int i = tid; i < 588; i += 256) {
        int r = i / 98, c = i - r * 98;
        int y = y0 - 1 + r, cx = c - 1;
        char* cell = lds + i * 80;
        if (((unsigned)y < 96u) && ((unsigned)cx < 96u)) {
            const float* xp = xf + ((size_t)y * 96 + cx) * 16;
            unsigned hp_[8], lp_[8];
            #pragma unroll
            for (int q = 0; q < 4; ++q) {
                f32x4 v = *(const f32x4*)(xp + q * 4);
                unsigned short ha = f2bf(v[0]), hb = f2bf(v[1]);
                unsigned short hc = f2bf(v[2]), hd = f2bf(v[3]);
                unsigned short la = f2bf(v[0] - bf2f(ha)), lb = f2bf(v[1] - bf2f(hb));
                unsigned short lc = f2bf(v[2] - bf2f(hc)), ld = f2bf(v[3] - bf2f(hd));
                hp_[q * 2]     = (unsigned)ha | ((unsigned)hb << 16);
                hp_[q * 2 + 1] = (unsigned)hc | ((unsigned)hd << 16);
                lp_[q * 2]     = (unsigned)la | ((unsigned)lb << 16);
                lp_[q * 2 + 1] = (unsigned)lc | ((unsigned)ld << 16);
            }
            ((uint4*)cell)[0] = make_uint4(hp_[0], hp_[1], hp_[2], hp_[3]);
            ((uint4*)cell)[1] = make_uint4(hp_[4], hp_[5], hp_[6], hp_[7]);
            ((uint4*)cell)[2] = make_uint4(lp_[0], lp_[1], lp_[2], lp_[3]);
            ((uint4*)cell)[3] = make_uint4(lp_[4], lp_[5], lp_[6], lp_[7]);
        } else {
            uint4 z = make_uint4(0, 0, 0, 0);
            ((uint4*)cell)[0] = z; ((uint4*)cell)[1] = z;
            ((uint4*)cell)[2] = z; ((uint4*)cell)[3] = z;
        }
    }
    if (tid == 0) {
        char* zc = lds + 588 * 80;
        uint4 z = make_uint4(0, 0, 0, 0);
        ((uint4*)zc)[0] = z; ((uint4*)zc)[1] = z; ((uint4*)zc)[2] = z; ((uint4*)zc)[3] = z;
    }
    __syncthreads();

    const int lane = tid & 63;
    const int w    = tid >> 6;
    const int lm   = lane & 15, lsec = lane >> 4;
    const int sel  = lsec >> 1;
    const int hioff = (lsec & 1) * 16, looff = 32 + (lsec & 1) * 16;

    f32x4 acc[6][4];
    #pragma unroll
    for (int nt = 0; nt < 4; ++nt) {
        float bv = bias[nt * 16 + lm];
        #pragma unroll
        for (int m = 0; m < 6; ++m) acc[m][nt] = (f32x4){bv, bv, bv, bv};
    }

    const int DY[10] = {-1,-1,-1, 0,0,0, 1,1,1, 0};
    const int DX[10] = {-1, 0, 1,-1,0,1,-1,0,1, 0};
    const short8v* BH = (const short8v*)Wph;
    const short8v* BL = (const short8v*)Wpl;

    #pragma unroll
    for (int kt = 0; kt < 5; ++kt) {
        short8v bh[4], bl[4];
        #pragma unroll
        for (int nt = 0; nt < 4; ++nt) {
            bh[nt] = BH[(kt * 4 + nt) * 64 + lane];
            bl[nt] = BL[(kt * 4 + nt) * 64 + lane];
        }
        const int dy = sel ? DY[2 * kt + 1] : DY[2 * kt];
        const int dx = sel ? DX[2 * kt + 1] : DX[2 * kt];
        const int r  = w + dy + 1;
        #pragma unroll
        for (int m = 0; m < 6; ++m) {
            int c = 1 + m * 16 + lm + dx;
            int cell = (r * 98 + c) * 80;
            if (kt == 4 && sel) cell = 588 * 80;
            short8v ah = *(const short8v*)(lds + cell + hioff);
            short8v al = *(const short8v*)(lds + cell + looff);
            #pragma unroll
            for (int nt = 0; nt < 4; ++nt)
                acc[m][nt] = __builtin_amdgcn_mfma_f32_16x16x32_bf16(ah, bh[nt], acc[m][nt], 0, 0, 0);
            #pragma unroll
            for (int nt = 0; nt < 4; ++nt)
                acc[m][nt] = __builtin_amdgcn_mfma_f32_16x16x32_bf16(al, bh[nt], acc[m][nt], 0, 0, 0);
            #pragma unroll
            for (int nt = 0; nt < 4; ++nt)
                acc[m][nt] = __builtin_amdgcn_mfma_f32_16x16x32_bf16(ah, bl[nt], acc[m][nt], 0, 0, 0);
        }
    }

    uint2* xzu = (uint2*)xz;
    const size_t fr = (size_t)(b * T_ + t);
    #pragma unroll
    for (int m = 0; m < 6; ++m) {
        size_t mt = (size_t)(y0 + w) * 6 + m;
        #pragma unroll
        for (int nt = 0; nt < 4; ++nt) {
            union { __half h[4]; uint2 u; } pk;
            #pragma unroll
            for (int j = 0; j < 4; ++j) pk.h[j] = __float2half_rn(acc[m][nt][j]);
            xzu[((fr * NMT_ + mt) * 4 + nt) * 64 + lane] = pk.u;
        }
    }
}

// ---------------------------------------------------------------------------
// Phase 2: serial LSTM step. Block: 128 thr = 2 waves, 2 rows. N=64/wave.
// acc init from xz fragments; stage only h (hi/lo bf16); per-lane epilogue
// (gate = nt, filter = lm). Dense(1) fused at t=23 via shfl_xor reduce.
// ---------------------------------------------------------------------------
__global__ __launch_bounds__(128) void lstm_step(
    const __half* __restrict__ xz,
    const unsigned short* __restrict__ Uph, const unsigned short* __restrict__ Upl,
    const unsigned short* __restrict__ hprev,  // [b][pt][16 hi][16 lo]
    unsigned short* __restrict__ hnew,
    float* __restrict__ cstate,                // [b][pt][16] f32
    const float* __restrict__ dw, const float* __restrict__ db,
    float* __restrict__ outp,                  // non-null at t=23
    int t)
{
    __shared__ __align__(16) char lds[393 * 80];
    const int tid  = threadIdx.x;
    const int y0   = blockIdx.x * 2;
    const int b    = blockIdx.y;
    const int lane = tid & 63;
    const int w    = tid >> 6;
    const int lm   = lane & 15, lsec = lane >> 4;
    const int sel  = lsec >> 1;
    const int hioff = (lsec & 1) * 16, looff = 32 + (lsec & 1) * 16;

    // acc init from xz (issue loads early; overlap with h staging)
    f32x4 acc[6][4];
    {
        const uint2* xzu = (const uint2*)xz;
        const size_t fr = (size_t)(b * T_ + t);
        #pragma unroll
        for (int m = 0; m < 6; ++m) {
            size_t mt = (size_t)(y0 + w) * 6 + m;
            #pragma unroll
            for (int nt = 0; nt < 4; ++nt) {
                union { uint2 u; __half h[4]; } pk;
                pk.u = xzu[((fr * NMT_ + mt) * 4 + nt) * 64 + lane];
                acc[m][nt] = (f32x4){__half2float(pk.h[0]), __half2float(pk.h[1]),
                                     __half2float(pk.h[2]), __half2float(pk.h[3])};
            }
        }
    }

    // stage h tile
    const unsigned short* hb = hprev + (size_t)b * HW_ * 32;
    for (int i = tid; i < 392; i += 128) {
        int r = i / 98, c = i - r * 98;
        int y = y0 - 1 + r, cx = c - 1;
        char* cell = lds + i * 80;
        if (((unsigned)y < 96u) && ((unsigned)cx < 96u)) {
            const uint4* s = (const uint4*)(hb + ((size_t)y * 96 + cx) * 32);
            ((uint4*)cell)[0] = s[0]; ((uint4*)cell)[1] = s[1];
            ((uint4*)cell)[2] = s[2]; ((uint4*)cell)[3] = s[3];
        } else {
            uint4 z = make_uint4(0, 0, 0, 0);
            ((uint4*)cell)[0] = z; ((uint4*)cell)[1] = z;
            ((uint4*)cell)[2] = z; ((uint4*)cell)[3] = z;
        }
    }
    if (tid == 0) {
        char* zc = lds + 392 * 80;
        uint4 z = make_uint4(0, 0, 0, 0);
        ((uint4*)zc)[0] = z; ((uint4*)zc)[1] = z; ((uint4*)zc)[2] = z; ((uint4*)zc)[3] = z;
    }
    __syncthreads();

    const int DY[10] = {-1,-1,-1, 0,0,0, 1,1,1, 0};
    const int DX[10] = {-1, 0, 1,-1,0,1,-1,0,1, 0};
    const short8v* BH = (const short8v*)Uph;
    const short8v* BL = (const short8v*)Upl;

    #pragma unroll
    for (int kt = 0; kt < 5; ++kt) {
        short8v bh[4], bl[4];
        #pragma unroll
        for (int nt = 0; nt < 4; ++nt) {
            bh[nt] = BH[(kt * 4 + nt) * 64 + lane];
            bl[nt] = BL[(kt * 4 + nt) * 64 + lane];
        }
        const int dy = sel ? DY[2 * kt + 1] : DY[2 * kt];
        const int dx = sel ? DX[2 * kt + 1] : DX[2 * kt];
        const int r  = w + dy + 1;
        #pragma unroll
        for (int m = 0; m < 6; ++m) {
            int c = 1 + m * 16 + lm + dx;
            int cell = (r * 98 + c) * 80;
            if (kt == 4 && sel) cell = 392 * 80;
            short8v ah = *(const short8v*)(lds + cell + hioff);
            short8v al = *(const short8v*)(lds + cell + looff);
            #pragma unroll
            for (int nt = 0; nt < 4; ++nt)
                acc[m][nt] = __builtin_amdgcn_mfma_f32_16x16x32_bf16(ah, bh[nt], acc[m][nt], 0, 0, 0);
            #pragma unroll
            for (int nt = 0; nt < 4; ++nt)
                acc[m][nt] = __builtin_amdgcn_mfma_f32_16x16x32_bf16(al, bh[nt], acc[m][nt], 0, 0, 0);
            #pragma unroll
            for (int nt = 0; nt < 4; ++nt)
                acc[m][nt] = __builtin_amdgcn_mfma_f32_16x16x32_bf16(ah, bl[nt], acc[m][nt], 0, 0, 0);
        }
    }

    // per-lane epilogue: point px = m*16 + lsec*4 + j, filter = lm, gate = nt
    const int y = y0 + w;
    const float dwv = dw[lm];
    const float db0 = db[0];
    #pragma unroll
    for (int m = 0; m < 6; ++m) {
        #pragma unroll
        for (int j = 0; j < 4; ++j) {
            int px = m * 16 + lsec * 4 + j;
            size_t pt = (size_t)b * HW_ + (size_t)y * 96 + px;
            float cp = cstate[pt * 16 + lm];
            float vi = sigm(acc[m][0][j]);
            float vf = sigm(acc[m][1][j]);
            float vg = fmaxf(acc[m][2][j], 0.f);
            float vo = sigm(acc[m][3][j]);
            float cn = vf * cp + vi * vg;
            cstate[pt * 16 + lm] = cn;
            float hn = vo * fmaxf(cn, 0.f);
            unsigned short hh = f2bf(hn);
            hnew[pt * 32 + lm]      = hh;
            hnew[pt * 32 + 16 + lm] = f2bf(hn - bf2f(hh));
            if (outp) {
                float v = hn * dwv;
                v += __shfl_xor(v, 1);
                v += __shfl_xor(v, 2);
                v += __shfl_xor(v, 4);
                v += __shfl_xor(v, 8);
                if (lm == 0) outp[pt] = v + db0;
            }
        }
    }
}

extern "C" void kernel_launch(void* const* d_in, const int* in_sizes, int n_in,
                              void* d_out, int out_size, void* d_ws, size_t ws_size,
                              hipStream_t stream) {
    const float* inputs = (const float*)d_in[0];
    const float* Wk     = (const float*)d_in[1];
    const float* Uk     = (const float*)d_in[2];
    const float* bias   = (const float*)d_in[3];
    const float* dw     = (const float*)d_in[4];
    const float* db     = (const float*)d_in[5];
    float* out = (float*)d_out;

    char* ws = (char*)d_ws;
    __half* xz = (__half*)ws;                           // 452,984,832 B
    size_t off = 452984832ull;
    unsigned short* h0 = (unsigned short*)(ws + off); off += 9437184;
    unsigned short* h1 = (unsigned short*)(ws + off); off += 9437184;
    float*          cc = (float*)(ws + off);          off += 9437184;
    unsigned short* Wph = (unsigned short*)(ws + off); off += 20480;
    unsigned short* Wpl = (unsigned short*)(ws + off); off += 20480;
    unsigned short* Uph = (unsigned short*)(ws + off); off += 20480;
    unsigned short* Upl = (unsigned short*)(ws + off); off += 20480;

    pack_w<<<40, 256, 0, stream>>>(Wk, Uk, Wph, Wpl, Uph, Upl);
    hipMemsetAsync(h0, 0, 9437184, stream);
    hipMemsetAsync(cc, 0, 9437184, stream);

    xconv<<<dim3(24, T_, B_), 256, 0, stream>>>(inputs, Wph, Wpl, bias, xz);

    for (int t = 0; t < T_; ++t) {
        const unsigned short* hp = (t & 1) ? h1 : h0;
        unsigned short*       hn = (t & 1) ? h0 : h1;
        lstm_step<<<dim3(48, B_), 128, 0, stream>>>(
            xz, Uph, Upl, hp, hn, cc, dw, db,
            (t == T_ - 1) ? out : (float*)nullptr, t);
    }
    (void)in_sizes; (void)n_in; (void)out_size; (void)ws_size;
}